// Round 4
// baseline (263.698 us; speedup 1.0000x reference)
//
#include <hip/hip_runtime.h>
#include <hip/hip_bf16.h>
#include <hip/hip_fp16.h>

// Pipeline:
//  x (4,64,130,130) --conv3x3 valid + bias + maxpool2x2--> p1 (4,64,64,64)
//  p1 --1x1 conv (64->32)--> t2 (4,32,64,64)
//  t2 --3x3 conv pad=1 (32->32)--> t3 (4,32,64,64)
//  [FUSED] offset conv (32->1152) computed INSIDE k_deform via f16 MFMA
//  deform_conv(x, upsample2x(offsets), wd) -> out (4,64,128,128)
//
//  k_deform v6 (per-sub-phase A-tile, 4 blocks/CU):
//   - v5 was latency-bound at 3 blocks/CU (LDS 51.7KB); grid wants 4/CU.
//   - A-tile now consumed per sub-phase (144 cols + 16 ZERO-pad cols = 160,
//     5 K=32 MFMA steps; zero A-cols kill the pad contribution). Pitch 192,
//     same XOR swizzle family. alds 24.6KB; total LDS 35.1KB -> 4 blocks/CU,
//     whole 1024-block grid co-resident (no tail), finer MFMA/gather
//     interleave across blocks.
//   - wdtb rows over-read by <=16 shorts at the padded K-step (x0 factor);
//     a zeroed 16-short tail pad guards the last row against 0*NaN.
//   - Offset MFMA (f16), gather fast path, epilogue unchanged (v5-proven).

#define HX 130
#define WX 130

typedef short bf16x8 __attribute__((ext_vector_type(8)));
typedef _Float16 f16x8 __attribute__((ext_vector_type(8)));
typedef float f32x4 __attribute__((ext_vector_type(4)));

static __device__ __forceinline__ unsigned short f2bf(float f) {
    unsigned u = __float_as_uint(f);
    unsigned r = u + 0x7fff + ((u >> 16) & 1);   // round-to-nearest-even
    return (unsigned short)(r >> 16);
}

// A-tile address (in shorts): row pitch 192 (24 16B-blocks), 16B-block swizzle
// col 0..159 -> blk 0..19 -> swz = blk ^ (row&7) <= 23 < 24. Row stride
// 384 B == 0 mod 128 -> XOR supplies the bank spread (same family as v5).
static __device__ __forceinline__ int aoff(int row, int col) {
    return row * 192 + ((((col >> 3) ^ (row & 7))) << 3) + (col & 7);
}

// ---------------- K0: wd -> bf16 wdtb[h(2)][oc(64)][col(288)] (+16 zero pad)
//                 and w3 -> fp16 w3h[1152][32]
// grid 288: idx<36864 -> wd, else w3. Threads 0..15 also zero the wdtb tail.
__global__ __launch_bounds__(256) void k_wdt(const float* __restrict__ wd,
                                             const float* __restrict__ w3,
                                             unsigned short* __restrict__ wdtb,
                                             __half* __restrict__ w3h) {
    int idx = blockIdx.x * 256 + threadIdx.x;
    if (idx < 36864) {
        int o = idx / 576;
        int rem = idx - o * 576;
        int c = rem / 9;
        int kk = rem - c * 9;
        int h = c >> 5;
        int c5 = c & 31;
        int col = (c5 >> 4) * 144 + ((c5 >> 3) & 1) * 72 + (c5 & 7) * 9 + kk;
        wdtb[(size_t)(h * 64 + o) * 288 + col] = f2bf(wd[idx]);
        if (idx < 16) wdtb[36864 + idx] = 0;   // tail pad: guard 0*NaN
    } else {
        int i2 = idx - 36864;
        if (i2 < 36864) w3h[i2] = __float2half_rn(w3[i2]);
    }
}

// ---------------- K1: conv3x3 valid (64->64) + bias + maxpool 2x2 -> p1
// grid 1024 = b(4) * cog(16, 4 oc) * tile(16, 4 pooled rows); block 256
__global__ __launch_bounds__(256, 4) void k_conv0_pool(const float* __restrict__ x,
                                                       const float* __restrict__ w0,
                                                       const float* __restrict__ b0,
                                                       float* __restrict__ p1) {
    int idx = blockIdx.x;
    int tile = idx & 15;          // 4 pooled rows each
    int cog = (idx >> 4) & 15;    // blockIdx-derived -> weight loads scalar
    int b = idx >> 8;
    int tid = threadIdx.x;
    int pw = tid & 63;
    int phl = tid >> 6;           // 0..3
    int ph = tile * 4 + phl;
    __shared__ float slab[2][10 * WX];        // 2 ci x 1300 floats
    const float* xb = x + (size_t)(b * 64) * HX * WX;
    int row0 = tile * 8;          // x rows row0..row0+9
    const float* xbase = xb + row0 * WX;
    float acc[4][4];
    #pragma unroll
    for (int i = 0; i < 4; ++i)
        #pragma unroll
        for (int j = 0; j < 4; ++j) acc[i][j] = 0.f;

    float pre[11];
    #pragma unroll
    for (int j = 0; j < 11; ++j) {
        int i = tid + j * 256;    // 0..2599 covers both ci slabs
        int ci = i / 1300, off = i - ci * 1300;
        pre[j] = (i < 2600) ? xbase[(size_t)ci * (HX * WX) + off] : 0.f;
    }

    for (int cg = 0; cg < 32; ++cg) {         // 2 ci per stage
        __syncthreads();
        #pragma unroll
        for (int j = 0; j < 11; ++j) {
            int i = tid + j * 256;
            if (i < 2600) ((float*)slab)[i] = pre[j];
        }
        __syncthreads();
        if (cg < 31) {
            const float* xp = xbase + (size_t)(2 * cg + 2) * (HX * WX);
            #pragma unroll
            for (int j = 0; j < 11; ++j) {
                int i = tid + j * 256;
                int ci = i / 1300, off = i - ci * 1300;
                pre[j] = (i < 2600) ? xp[(size_t)ci * (HX * WX) + off] : 0.f;
            }
        }
        #pragma unroll
        for (int lc = 0; lc < 2; ++lc) {
            int ci = 2 * cg + lc;
            float v[4][4];
            #pragma unroll
            for (int r2 = 0; r2 < 4; ++r2) {
                const float* rp = &slab[lc][(2 * phl + r2) * WX + 2 * pw];
                float2 a = *(const float2*)rp;
                float2 bb = *(const float2*)(rp + 2);
                v[r2][0] = a.x; v[r2][1] = a.y; v[r2][2] = bb.x; v[r2][3] = bb.y;
            }
            #pragma unroll
            for (int i = 0; i < 4; ++i) {
                const float* wp = w0 + (((cog * 4 + i) * 64) + ci) * 9;  // uniform
                float w[9];
                #pragma unroll
                for (int k = 0; k < 9; ++k) w[k] = wp[k];
                #pragma unroll
                for (int dr = 0; dr < 2; ++dr)
                    #pragma unroll
                    for (int dc = 0; dc < 2; ++dc) {
                        float s = acc[i][dr * 2 + dc];
                        #pragma unroll
                        for (int ky = 0; ky < 3; ++ky)
                            #pragma unroll
                            for (int kx = 0; kx < 3; ++kx)
                                s += w[ky * 3 + kx] * v[dr + ky][dc + kx];
                        acc[i][dr * 2 + dc] = s;
                    }
            }
        }
    }
    #pragma unroll
    for (int i = 0; i < 4; ++i) {
        float m = fmaxf(fmaxf(acc[i][0], acc[i][1]), fmaxf(acc[i][2], acc[i][3]))
                + b0[cog * 4 + i];
        p1[(((size_t)b * 64 + cog * 4 + i) * 64 + ph) * 64 + pw] = m;
    }
}

// ---------------- K2: 1x1 conv 64->32 on 64x64; grid 1024 (2 oc/thread)
__global__ __launch_bounds__(256) void k_conv1x1_a(const float* __restrict__ p1,
                                                   const float* __restrict__ w1,
                                                   const float* __restrict__ b1,
                                                   float* __restrict__ t2) {
    int blk = blockIdx.x;
    int pt = blk & 15;
    int cog = (blk >> 4) & 15;
    int b = blk >> 8;
    int p = pt * 256 + threadIdx.x;
    float acc[2];
    #pragma unroll
    for (int i = 0; i < 2; ++i) acc[i] = b1[cog * 2 + i];
    const float* ip = p1 + (size_t)b * 64 * 4096 + p;
    for (int ci = 0; ci < 64; ++ci) {
        float v = ip[(size_t)ci * 4096];
        #pragma unroll
        for (int i = 0; i < 2; ++i) acc[i] += w1[(cog * 2 + i) * 64 + ci] * v;
    }
    float* op = t2 + (size_t)b * 32 * 4096 + p;
    #pragma unroll
    for (int i = 0; i < 2; ++i) op[(size_t)(cog * 2 + i) * 4096] = acc[i];
}

// ---------------- K3: 3x3 conv pad=1, 32->32 on 64x64; grid 1024 (2 oc/thread)
__global__ __launch_bounds__(256) void k_conv3x3_b(const float* __restrict__ t2,
                                                   const float* __restrict__ w2,
                                                   const float* __restrict__ b2,
                                                   float* __restrict__ t3) {
    int blk = blockIdx.x;
    int pt = blk & 15;
    int cog = (blk >> 4) & 15;
    int b = blk >> 8;
    int p = pt * 256 + threadIdx.x;
    int hy = p >> 6, wx = p & 63;
    float acc[2];
    #pragma unroll
    for (int i = 0; i < 2; ++i) acc[i] = b2[cog * 2 + i];
    const float* ip = t2 + (size_t)b * 32 * 4096;
    for (int ci = 0; ci < 32; ++ci) {
        float v[9];
        #pragma unroll
        for (int ky = 0; ky < 3; ++ky) {
            int yy = hy + ky - 1;
            #pragma unroll
            for (int kx = 0; kx < 3; ++kx) {
                int xx = wx + kx - 1;
                bool ok = (yy >= 0 && yy < 64 && xx >= 0 && xx < 64);
                int yc = min(max(yy, 0), 63), xc = min(max(xx, 0), 63);
                float val = ip[(size_t)ci * 4096 + yc * 64 + xc];
                v[ky * 3 + kx] = ok ? val : 0.f;
            }
        }
        #pragma unroll
        for (int i = 0; i < 2; ++i) {
            const float* wp = w2 + (((cog * 2 + i) * 32) + ci) * 9;   // uniform
            float s = acc[i];
            #pragma unroll
            for (int k = 0; k < 9; ++k) s += wp[k] * v[k];
            acc[i] = s;
        }
    }
    float* op = t3 + (size_t)b * 32 * 4096 + p;
    #pragma unroll
    for (int i = 0; i < 2; ++i) op[(size_t)(cog * 2 + i) * 4096] = acc[i];
}

// ---------------- K5: deformable conv, MFMA offsets + MFMA main (v6)
// grid 1024 = strip(256)*4 + b. block 256 = 4 waves, all-resident (4/CU).
// Per sub-phase s: 18 f16-MFMA offset tiles -> soff; 2304 gathers -> A-tile
// [64px][144+16pad]; 5 K=32 x 4 N bf16-MFMA accumulate D[64px][64oc].
__global__ __launch_bounds__(256, 4) void k_deform(const float* __restrict__ x,
                                                   const float* __restrict__ t3,
                                                   const __half* __restrict__ w3h,
                                                   const float* __restrict__ b3,
                                                   const unsigned short* __restrict__ wdtb,
                                                   float* __restrict__ out) {
    int blk = blockIdx.x;
    int b = blk & 3;
    int strip = blk >> 2;         // 0..255
    int tid = threadIdx.x;
    int po0 = strip * 16;
    int qy = po0 >> 6;            // strip lies in one quad-row
    int qx0 = po0 & 63;
    int w = tid >> 6;             // wave id
    int lane = tid & 63;
    int lm = lane & 15;
    int lq = lane >> 4;
    int tq = tid & 15;            // pooled-px column this thread serves (fixed)
    int kb = tid >> 4;            // kcol = it*16 + kb

    __shared__ __align__(16) unsigned short alds[64 * 192];   // 24576 B
    __shared__ __align__(16) __half2 soff[2304];              //  9216 B
    __shared__ __align__(16) _Float16 st3t[16 * 40];          //  1280 B

    f32x4 acc[4];
    #pragma unroll
    for (int n = 0; n < 4; ++n) acc[n] = (f32x4){0.f, 0.f, 0.f, 0.f};

    const float* xb = x + (size_t)b * 64 * HX * WX;
    float fybase = (float)(2 * qy);
    float fxbase = (float)(2 * (qx0 + tq));

    // ---- stage t3 tile (32 ci x 16 px) to LDS as fp16, px-major pitch 40
    {
        int px = tid & 15, ci0 = tid >> 4;    // ci0 0..15
        const float* t3p = t3 + (size_t)b * 32 * 4096 + (qy * 64 + qx0 + px);
        st3t[px * 40 + ci0]      = (_Float16)t3p[(size_t)ci0 * 4096];
        st3t[px * 40 + ci0 + 16] = (_Float16)t3p[(size_t)(ci0 + 16) * 4096];
    }
    // ---- zero the A-tile pad cols 144..159 (persist: gathers write <144)
    if (tid < 128) {
        *(bf16x8*)&alds[aoff(tid >> 1, 144 + (tid & 1) * 8)] =
            (bf16x8){0, 0, 0, 0, 0, 0, 0, 0};
    }
    __syncthreads();
    // B-frag (t3) for the offset MFMA: lane holds t3[px=lm][ci=lq*8+j].
    const f16x8 bfrag = *(const f16x8*)&st3t[lm * 40 + lq * 8];

    for (int h = 0; h < 2; ++h) {
        #pragma unroll 1
        for (int sl = 0; sl < 2; ++sl) {
            int s = h * 2 + sl;           // sup = 16 channels

            // ---- phase 1a: offsets via f16 MFMA. 18 tiles of 16 off-ch.
            // (soff reuse safe: prev iter's reads finished before its
            //  pre-phase2 barrier; alds untouched here.)
            #pragma unroll
            for (int rep = 0; rep < 5; ++rep) {
                int t = rep * 4 + w;
                if (rep == 4) { if (w >= 2) break; t = 16 + w; }
                const f16x8 afrag = *(const f16x8*)((const _Float16*)w3h
                        + (size_t)(s * 288 + t * 16 + lm) * 32 + lq * 8);
                f32x4 d = __builtin_amdgcn_mfma_f32_16x16x32_f16(
                        afrag, bfrag, (f32x4){0.f, 0.f, 0.f, 0.f}, 0, 0, 0);
                float4 bq = *(const float4*)(b3 + s * 288 + t * 16 + lq * 4);
                int p0 = (t * 8 + lq * 2) * 16 + lm;   // pair-slot kcol*16+px
                soff[p0]      = __floats2half2_rn(d[0] + bq.x, d[1] + bq.y);
                soff[p0 + 16] = __floats2half2_rn(d[2] + bq.z, d[3] + bq.w);
            }
            __syncthreads();              // soff visible; prev phase2 done

            // ---- phase 1b: prefetch 9 offset pairs (word = it*256 + tid)
            __half2 o2h[9];
            #pragma unroll
            for (int it = 0; it < 9; ++it)
                o2h[it] = soff[it * 256 + tid];
            // bilinear gather -> 4 bf16 A-tile rows per task
            #pragma unroll
            for (int it = 0; it < 9; ++it) {
                int kcol = it * 16 + kb;      // 0..143
                int lc = kcol >= 72;
                int ckk = kcol - 72 * lc;     // 0..71
                int ch = (ckk * 57) >> 9;     // /9
                int kk = ckk - ch * 9;
                int c = s * 16 + lc * 8 + ch;
                int clocal = kcol;            // A column 0..143
                float2 off = __half22float2(o2h[it]);
                float py = off.x + fybase + (float)(kk / 3);
                float px = off.y + fxbase + (float)(kk % 3);
                float y0f = floorf(py), x0f = floorf(px);
                float fy = py - y0f, fx = px - x0f;
                int y0 = (int)y0f, x0 = (int)x0f;
                const float* xp = xb + (size_t)c * (HX * WX);
                float tv[3][3];
                bool fastok = (y0 >= 0) & (y0 <= HX - 3) & (x0 >= 0) & (x0 <= WX - 3);
                if (__all(fastok)) {
                    // whole wave in-bounds: even-aligned float2 pair per row
                    int xe = x0 & ~1;         // even -> 8B-aligned (WX even)
                    int odd = x0 & 1;
                    const float* rp = xp + y0 * WX + xe;
                    #pragma unroll
                    for (int r = 0; r < 3; ++r) {
                        float2 A = *(const float2*)(rp);
                        float2 B = *(const float2*)(rp + 2);
                        tv[r][0] = odd ? A.y : A.x;
                        tv[r][1] = odd ? B.x : A.y;
                        tv[r][2] = odd ? B.y : B.x;
                        rp += WX;
                    }
                } else {
                    #pragma unroll
                    for (int r = 0; r < 3; ++r) {
                        int yy = y0 + r;
                        bool vy = (yy >= 0) & (yy < HX);
                        int yc = min(max(yy, 0), HX - 1);
                        #pragma unroll
                        for (int sx = 0; sx < 3; ++sx) {
                            int xx = x0 + sx;
                            bool vx = (xx >= 0) & (xx < WX);
                            int xc = min(max(xx, 0), WX - 1);
                            float val = xp[yc * WX + xc];
                            tv[r][sx] = (vy & vx) ? val : 0.f;
                        }
                    }
                }
                float h0[3], h1[3];
                #pragma unroll
                for (int r = 0; r < 3; ++r) {
                    h0[r] = tv[r][0] + fx * (tv[r][1] - tv[r][0]);
                    h1[r] = tv[r][1] + fx * (tv[r][2] - tv[r][1]);
                }
                alds[aoff(0 * 16 + tq, clocal)] = f2bf(h0[0] + fy * (h0[1] - h0[0]));
                alds[aoff(1 * 16 + tq, clocal)] = f2bf(h1[0] + fy * (h1[1] - h1[0]));
                alds[aoff(2 * 16 + tq, clocal)] = f2bf(h0[1] + fy * (h0[2] - h0[1]));
                alds[aoff(3 * 16 + tq, clocal)] = f2bf(h1[1] + fy * (h1[2] - h1[1]));
            }
            __syncthreads();          // A-tile (144 cols + zero pad) visible

            // ---- phase 2: D[64px][64oc] += V[64][160] . W^T  (MFMA bf16)
            // cols 144..159 of A are zero -> pad K-steps contribute nothing.
            int arow = w * 16 + lm;
            const unsigned short* bbase = wdtb + (size_t)(h * 64) * 288 + sl * 144;
            #pragma unroll
            for (int ks = 0; ks < 5; ++ks) {
                bf16x8 a = *(const bf16x8*)&alds[aoff(arow, ks * 32 + lq * 8)];
                #pragma unroll
                for (int n = 0; n < 4; ++n) {
                    bf16x8 bb = *(const bf16x8*)(bbase + (size_t)(n * 16 + lm) * 288
                                                 + ks * 32 + lq * 8);
                    acc[n] = __builtin_amdgcn_mfma_f32_16x16x32_bf16(a, bb, acc[n], 0, 0, 0);
                }
            }
        }
    }

    // ---- epilogue via LDS: D lane layout -> [oc][px] -> coalesced stores
    __syncthreads();              // all phase-2 reads of alds complete
    float* dlds = (float*)alds;   // 64*65 = 4160 floats (16.6 KB of 24.6)
    #pragma unroll
    for (int n = 0; n < 4; ++n) {
        int oc = n * 16 + lm;
        #pragma unroll
        for (int r = 0; r < 4; ++r) {
            int px = w * 16 + lq * 4 + r;     // = sub*16 + q
            dlds[oc * 65 + px] = acc[n][r];
        }
    }
    __syncthreads();
    {
        int oc = tid >> 2;
        int sy = (tid >> 1) & 1;
        int qh = (tid & 1) * 8;
        float* orow = out + (((size_t)b * 64 + oc) * 128 + 2 * qy + sy) * 128 + 2 * qx0;
        const float* d0 = &dlds[oc * 65 + (sy * 2 + 0) * 16];
        const float* d1 = &dlds[oc * 65 + (sy * 2 + 1) * 16];
        #pragma unroll
        for (int i = 0; i < 8; ++i) {
            int q = qh + i;
            *(float2*)(orow + 2 * q) = make_float2(d0[q], d1[q]);
        }
    }
}

extern "C" void kernel_launch(void* const* d_in, const int* in_sizes, int n_in,
                              void* d_out, int out_size, void* d_ws, size_t ws_size,
                              hipStream_t stream) {
    const float* x  = (const float*)d_in[0];
    const float* w0 = (const float*)d_in[1];
    const float* b0 = (const float*)d_in[2];
    const float* w1 = (const float*)d_in[3];
    const float* b1 = (const float*)d_in[4];
    const float* w2 = (const float*)d_in[5];
    const float* b2 = (const float*)d_in[6];
    const float* w3 = (const float*)d_in[7];
    const float* b3 = (const float*)d_in[8];
    const float* wd = (const float*)d_in[9];
    float* out = (float*)d_out;

    float* ws = (float*)d_ws;
    float* p1    = ws;                       // 1,048,576 floats
    float* t2    = p1 + 1048576;             //   524,288
    float* t3    = t2 + 524288;              //   524,288
    unsigned short* wdtb = (unsigned short*)(t3 + 524288);  // 36,864 bf16 + 16 pad
    __half* w3h = (__half*)(wdtb + 36880);   // 36,864 fp16 (16B-aligned: 36880*2)

    k_wdt<<<288, 256, 0, stream>>>(wd, w3, wdtb, w3h);
    k_conv0_pool<<<1024, 256, 0, stream>>>(x, w0, b0, p1);
    k_conv1x1_a<<<1024, 256, 0, stream>>>(p1, w1, b1, t2);
    k_conv3x3_b<<<1024, 256, 0, stream>>>(t2, w2, b2, t3);
    k_deform<<<1024, 256, 0, stream>>>(x, t3, w3h, b3, wdtb, out);
}

// Round 5
// 226.756 us; speedup vs baseline: 1.1629x; 1.1629x over previous
//
#include <hip/hip_runtime.h>
#include <hip/hip_bf16.h>
#include <hip/hip_fp16.h>

// Pipeline:
//  x (4,64,130,130) --conv3x3 valid + bias + maxpool2x2 (MFMA)--> p1 (4,64,64,64)
//  p1 --1x1 conv (64->32)--> t2 (4,32,64,64)
//  t2 --3x3 conv pad=1 (32->32)--> t3 (4,32,64,64)
//  [FUSED] offset conv (32->1152) computed INSIDE k_deform via f16 MFMA
//  deform_conv(x, upsample2x(offsets), wd) -> out (4,64,128,128)
//
//  Round-5 changes:
//   - k_deform REVERTED to v5 verbatim (84 us proven; v6's 4/CU variant
//     re-spilled ~10MB scratch under the 128-VGPR cap and regressed).
//   - k_conv0_pool replaced by k_conv0_mfma: same A-tile/B-row/epilogue
//     conventions as k_deform phase-2 (proven lane mappings), 8x8 conv-px
//     region per block, K=576 over 4 ci-groups of 144 (+16 zero pad),
//     bf16 MFMA, 2x2 maxpool + bias in epilogue. ~5x the fp32 VALU path.
//   - k_wdt additionally packs w0 -> bf16 w0b[cig(4)][oc(64)][160] rows.

#define HX 130
#define WX 130

typedef short bf16x8 __attribute__((ext_vector_type(8)));
typedef _Float16 f16x8 __attribute__((ext_vector_type(8)));
typedef float f32x4 __attribute__((ext_vector_type(4)));

static __device__ __forceinline__ unsigned short f2bf(float f) {
    unsigned u = __float_as_uint(f);
    unsigned r = u + 0x7fff + ((u >> 16) & 1);   // round-to-nearest-even
    return (unsigned short)(r >> 16);
}

// A-tile address (in shorts): row pitch 320, 16B-block swizzle (k_deform v5)
static __device__ __forceinline__ int aoff320(int row, int col) {
    return row * 320 + ((((col >> 3) ^ (row & 7))) << 3) + (col & 7);
}

// A-tile address (in shorts): row pitch 192 (conv0 MFMA, 160 cols)
static __device__ __forceinline__ int aoff192(int row, int col) {
    return row * 192 + ((((col >> 3) ^ (row & 7))) << 3) + (col & 7);
}

// ---------------- K0: weight prep
//  idx <  36864 : wd -> bf16 wdtb[h(2)][oc(64)][col(288)]  (+16 zero tail)
//  idx <  73728 : w3 -> fp16 w3h[1152][32]
//  idx < 114688 : w0 -> bf16 w0b[cig(4)][oc(64)][160]; col=ci_l*9+kk, pad 0
__global__ __launch_bounds__(256) void k_wdt(const float* __restrict__ wd,
                                             const float* __restrict__ w3,
                                             const float* __restrict__ w0,
                                             unsigned short* __restrict__ wdtb,
                                             __half* __restrict__ w3h,
                                             unsigned short* __restrict__ w0b) {
    int idx = blockIdx.x * 256 + threadIdx.x;   // grid 448*256 = 114688
    if (idx < 36864) {
        int o = idx / 576;
        int rem = idx - o * 576;
        int c = rem / 9;
        int kk = rem - c * 9;
        int h = c >> 5;
        int c5 = c & 31;
        int col = (c5 >> 4) * 144 + ((c5 >> 3) & 1) * 72 + (c5 & 7) * 9 + kk;
        wdtb[(size_t)(h * 64 + o) * 288 + col] = f2bf(wd[idx]);
        if (idx < 16) wdtb[36864 + idx] = 0;    // tail pad (harmless for v5)
    } else if (idx < 73728) {
        int i2 = idx - 36864;
        w3h[i2] = __float2half_rn(w3[i2]);
    } else {
        int i3 = idx - 73728;                   // 0..40959
        int row = i3 / 160;                     // cig*64 + oc
        int col = i3 - row * 160;
        int cig = row >> 6, oc = row & 63;
        unsigned short v = 0;
        if (col < 144) {
            int ci = (col * 57) >> 9;           // /9, valid col<144
            int kk = col - ci * 9;
            v = f2bf(w0[(size_t)(oc * 64 + cig * 16 + ci) * 9 + kk]);
        }
        w0b[i3] = v;
    }
}

// ---------------- K1: conv3x3 valid (64->64) via MFMA + bias + maxpool -> p1
// grid 1024 = b(4) * ty(16) * tx(16); block 256 = 4 waves.
// Block: conv-out region 8x8 at (ty*8, tx*8), all 64 oc.
// A[64 px][144+16pad] bf16 per ci-group (16 ci x 9 kk); B = w0b rows (160).
// Lane/fragment/epilogue conventions copied from k_deform phase-2 (proven).
__global__ __launch_bounds__(256, 4) void k_conv0_mfma(const float* __restrict__ x,
                                                       const unsigned short* __restrict__ w0b,
                                                       const float* __restrict__ b0,
                                                       float* __restrict__ p1) {
    int blk = blockIdx.x;
    int tx = blk & 15;
    int ty = (blk >> 4) & 15;
    int b = blk >> 8;
    int tid = threadIdx.x;
    int w = tid >> 6;
    int lane = tid & 63;
    int lm = lane & 15;
    int lq = lane >> 4;
    int oy0 = ty * 8, ox0 = tx * 8;

    __shared__ __align__(16) unsigned short alds[64 * 192];   // 24576 B
    __shared__ __align__(16) float xlds[1600];                //  6400 B

    f32x4 acc[4];
    #pragma unroll
    for (int n = 0; n < 4; ++n) acc[n] = (f32x4){0.f, 0.f, 0.f, 0.f};

    // zero A-tile pad cols 144..159 once (builds only write col<144)
    if (tid < 128) {
        *(bf16x8*)&alds[aoff192(tid >> 1, 144 + (tid & 1) * 8)] =
            (bf16x8){0, 0, 0, 0, 0, 0, 0, 0};
    }

    const float* xb = x + (size_t)(b * 64) * (HX * WX) + oy0 * WX + ox0;
    // build-A task mapping: 4 lanes per px row -> spread rows/cols over banks
    int apx = tid >> 2;           // 0..63 conv px (py*8+pxx)
    int acq = tid & 3;            // col slice
    int py = apx >> 3, pxx = apx & 7;

    for (int cig = 0; cig < 4; ++cig) {
        // ---- stage x tile: 16 ci x 10 x 10 fp32
        #pragma unroll
        for (int j = 0; j < 7; ++j) {
            int i = tid + j * 256;
            if (i < 1600) {
                int ci = i / 100;
                int rem = i - ci * 100;
                int rr = rem / 10, cc = rem - rr * 10;
                xlds[i] = xb[(size_t)(cig * 16 + ci) * (HX * WX) + rr * WX + cc];
            }
        }
        __syncthreads();          // xlds ready; prev MFMA's alds reads done
        // ---- build A: 36 cols per thread (col = acq*36 + jj)
        #pragma unroll
        for (int jj = 0; jj < 36; ++jj) {
            int col = acq * 36 + jj;
            int ci = (col * 57) >> 9;     // /9
            int kk = col - ci * 9;
            int ky = kk / 3, kx = kk - ky * 3;
            alds[aoff192(apx, col)] =
                f2bf(xlds[ci * 100 + (py + ky) * 10 + (pxx + kx)]);
        }
        __syncthreads();          // A-tile visible
        // ---- MFMA: D[64px][64oc] += A[64][160] . B^T (pad cols are zero)
        int arow = w * 16 + lm;
        const unsigned short* bbase = w0b + (size_t)cig * 64 * 160;
        #pragma unroll
        for (int ks = 0; ks < 5; ++ks) {
            bf16x8 a = *(const bf16x8*)&alds[aoff192(arow, ks * 32 + lq * 8)];
            #pragma unroll
            for (int n = 0; n < 4; ++n) {
                bf16x8 bb = *(const bf16x8*)(bbase + (size_t)(n * 16 + lm) * 160
                                             + ks * 32 + lq * 8);
                acc[n] = __builtin_amdgcn_mfma_f32_16x16x32_bf16(a, bb, acc[n], 0, 0, 0);
            }
        }
    }

    // ---- epilogue: D -> LDS [oc][px] -> 2x2 maxpool + bias -> p1
    __syncthreads();              // all MFMA reads of alds complete
    float* dlds = (float*)alds;   // 64*65 floats = 16640 B
    #pragma unroll
    for (int n = 0; n < 4; ++n) {
        int oc = n * 16 + lm;
        #pragma unroll
        for (int r = 0; r < 4; ++r) {
            int px = w * 16 + lq * 4 + r;
            dlds[oc * 65 + px] = acc[n][r];
        }
    }
    __syncthreads();
    {
        int oc = tid >> 2;
        int ppy = tid & 3;        // pooled row within 4x4 region
        float bo = b0[oc];
        float4 o4;
        #pragma unroll
        for (int ppx = 0; ppx < 4; ++ppx) {
            const float* dp = &dlds[oc * 65 + (2 * ppy) * 8 + 2 * ppx];
            float m = fmaxf(fmaxf(dp[0], dp[1]), fmaxf(dp[8], dp[9])) + bo;
            ((float*)&o4)[ppx] = m;
        }
        *(float4*)(p1 + (((size_t)b * 64 + oc) * 64 + ty * 4 + ppy) * 64 + tx * 4) = o4;
    }
}

// ---------------- K2: 1x1 conv 64->32 on 64x64; grid 1024 (2 oc/thread)
__global__ __launch_bounds__(256) void k_conv1x1_a(const float* __restrict__ p1,
                                                   const float* __restrict__ w1,
                                                   const float* __restrict__ b1,
                                                   float* __restrict__ t2) {
    int blk = blockIdx.x;
    int pt = blk & 15;
    int cog = (blk >> 4) & 15;
    int b = blk >> 8;
    int p = pt * 256 + threadIdx.x;
    float acc[2];
    #pragma unroll
    for (int i = 0; i < 2; ++i) acc[i] = b1[cog * 2 + i];
    const float* ip = p1 + (size_t)b * 64 * 4096 + p;
    for (int ci = 0; ci < 64; ++ci) {
        float v = ip[(size_t)ci * 4096];
        #pragma unroll
        for (int i = 0; i < 2; ++i) acc[i] += w1[(cog * 2 + i) * 64 + ci] * v;
    }
    float* op = t2 + (size_t)b * 32 * 4096 + p;
    #pragma unroll
    for (int i = 0; i < 2; ++i) op[(size_t)(cog * 2 + i) * 4096] = acc[i];
}

// ---------------- K3: 3x3 conv pad=1, 32->32 on 64x64; grid 1024 (2 oc/thread)
__global__ __launch_bounds__(256) void k_conv3x3_b(const float* __restrict__ t2,
                                                   const float* __restrict__ w2,
                                                   const float* __restrict__ b2,
                                                   float* __restrict__ t3) {
    int blk = blockIdx.x;
    int pt = blk & 15;
    int cog = (blk >> 4) & 15;
    int b = blk >> 8;
    int p = pt * 256 + threadIdx.x;
    int hy = p >> 6, wx = p & 63;
    float acc[2];
    #pragma unroll
    for (int i = 0; i < 2; ++i) acc[i] = b2[cog * 2 + i];
    const float* ip = t2 + (size_t)b * 32 * 4096;
    for (int ci = 0; ci < 32; ++ci) {
        float v[9];
        #pragma unroll
        for (int ky = 0; ky < 3; ++ky) {
            int yy = hy + ky - 1;
            #pragma unroll
            for (int kx = 0; kx < 3; ++kx) {
                int xx = wx + kx - 1;
                bool ok = (yy >= 0 && yy < 64 && xx >= 0 && xx < 64);
                int yc = min(max(yy, 0), 63), xc = min(max(xx, 0), 63);
                float val = ip[(size_t)ci * 4096 + yc * 64 + xc];
                v[ky * 3 + kx] = ok ? val : 0.f;
            }
        }
        #pragma unroll
        for (int i = 0; i < 2; ++i) {
            const float* wp = w2 + (((cog * 2 + i) * 32) + ci) * 9;   // uniform
            float s = acc[i];
            #pragma unroll
            for (int k = 0; k < 9; ++k) s += wp[k] * v[k];
            acc[i] = s;
        }
    }
    float* op = t3 + (size_t)b * 32 * 4096 + p;
    #pragma unroll
    for (int i = 0; i < 2; ++i) op[(size_t)(cog * 2 + i) * 4096] = acc[i];
}

// ---------------- K5: deformable conv, MFMA offsets + MFMA main (v5, proven)
// grid 1024 = strip(256)*4 + b. block 256 = 4 waves.
// Per sub-phase s (16 x-channels): 18 f16-MFMA tiles compute all 2304
// offset values -> soff (half2 py,px); then 2304 gather tasks fill the
// bf16 A-tile; per half h: 9x4 bf16-MFMA accumulate D[64px][64oc].
__global__ __launch_bounds__(256, 3) void k_deform(const float* __restrict__ x,
                                                   const float* __restrict__ t3,
                                                   const __half* __restrict__ w3h,
                                                   const float* __restrict__ b3,
                                                   const unsigned short* __restrict__ wdtb,
                                                   float* __restrict__ out) {
    int blk = blockIdx.x;
    int b = blk & 3;
    int strip = blk >> 2;         // 0..255
    int tid = threadIdx.x;
    int po0 = strip * 16;
    int qy = po0 >> 6;            // strip lies in one quad-row
    int qx0 = po0 & 63;
    int w = tid >> 6;             // wave id
    int lane = tid & 63;
    int lm = lane & 15;
    int lq = lane >> 4;
    int tq = tid & 15;            // pooled-px column this thread serves (fixed)
    int kb = tid >> 4;            // kcol = it*16 + kb

    __shared__ __align__(16) unsigned short alds[64 * 320];   // 40960 B
    __shared__ __align__(16) __half2 soff[2304];              //  9216 B
    __shared__ __align__(16) _Float16 st3t[16 * 40];          //  1280 B

    f32x4 acc[4];
    #pragma unroll
    for (int n = 0; n < 4; ++n) acc[n] = (f32x4){0.f, 0.f, 0.f, 0.f};

    const float* xb = x + (size_t)b * 64 * HX * WX;
    float fybase = (float)(2 * qy);
    float fxbase = (float)(2 * (qx0 + tq));

    // ---- stage t3 tile (32 ci x 16 px) to LDS as fp16, px-major pitch 40
    {
        int px = tid & 15, ci0 = tid >> 4;    // ci0 0..15
        const float* t3p = t3 + (size_t)b * 32 * 4096 + (qy * 64 + qx0 + px);
        st3t[px * 40 + ci0]      = (_Float16)t3p[(size_t)ci0 * 4096];
        st3t[px * 40 + ci0 + 16] = (_Float16)t3p[(size_t)(ci0 + 16) * 4096];
    }
    __syncthreads();
    // B-frag (t3) for the offset MFMA: lane holds t3[px=lm][ci=lq*8+j].
    const f16x8 bfrag = *(const f16x8*)&st3t[lm * 40 + lq * 8];

    for (int h = 0; h < 2; ++h) {
        #pragma unroll 1
        for (int sl = 0; sl < 2; ++sl) {
            int s = h * 2 + sl;           // sup = 16 channels
            __syncthreads();              // alds+soff free (prev phase done)

            // ---- phase 1a: offsets via f16 MFMA. 18 tiles of 16 off-ch.
            #pragma unroll
            for (int rep = 0; rep < 5; ++rep) {
                int t = rep * 4 + w;
                if (rep == 4) { if (w >= 2) break; t = 16 + w; }
                const f16x8 afrag = *(const f16x8*)((const _Float16*)w3h
                        + (size_t)(s * 288 + t * 16 + lm) * 32 + lq * 8);
                f32x4 d = __builtin_amdgcn_mfma_f32_16x16x32_f16(
                        afrag, bfrag, (f32x4){0.f, 0.f, 0.f, 0.f}, 0, 0, 0);
                float4 bq = *(const float4*)(b3 + s * 288 + t * 16 + lq * 4);
                int p0 = (t * 8 + lq * 2) * 16 + lm;   // pair-slot kcol*16+px
                soff[p0]      = __floats2half2_rn(d[0] + bq.x, d[1] + bq.y);
                soff[p0 + 16] = __floats2half2_rn(d[2] + bq.z, d[3] + bq.w);
            }
            __syncthreads();              // soff visible

            // ---- phase 1b: prefetch 9 offset pairs (word = it*256 + tid)
            __half2 o2h[9];
            #pragma unroll
            for (int it = 0; it < 9; ++it)
                o2h[it] = soff[it * 256 + tid];
            // bilinear gather -> 4 bf16 A-tile rows per task
            #pragma unroll
            for (int it = 0; it < 9; ++it) {
                int kcol = it * 16 + kb;      // 0..143
                int lc = kcol >= 72;
                int ckk = kcol - 72 * lc;     // 0..71
                int ch = (ckk * 57) >> 9;     // /9
                int kk = ckk - ch * 9;
                int c = s * 16 + lc * 8 + ch;
                int clocal = sl * 144 + kcol; // A column 0..287
                float2 off = __half22float2(o2h[it]);
                float py = off.x + fybase + (float)(kk / 3);
                float px = off.y + fxbase + (float)(kk % 3);
                float y0f = floorf(py), x0f = floorf(px);
                float fy = py - y0f, fx = px - x0f;
                int y0 = (int)y0f, x0 = (int)x0f;
                const float* xp = xb + (size_t)c * (HX * WX);
                float tv[3][3];
                bool fastok = (y0 >= 0) & (y0 <= HX - 3) & (x0 >= 0) & (x0 <= WX - 3);
                if (__all(fastok)) {
                    // whole wave in-bounds: even-aligned float2 pair per row
                    int xe = x0 & ~1;         // even -> 8B-aligned (WX even)
                    int odd = x0 & 1;
                    const float* rp = xp + y0 * WX + xe;
                    #pragma unroll
                    for (int r = 0; r < 3; ++r) {
                        float2 A = *(const float2*)(rp);
                        float2 B = *(const float2*)(rp + 2);
                        tv[r][0] = odd ? A.y : A.x;
                        tv[r][1] = odd ? B.x : A.y;
                        tv[r][2] = odd ? B.y : B.x;
                        rp += WX;
                    }
                } else {
                    #pragma unroll
                    for (int r = 0; r < 3; ++r) {
                        int yy = y0 + r;
                        bool vy = (yy >= 0) & (yy < HX);
                        int yc = min(max(yy, 0), HX - 1);
                        #pragma unroll
                        for (int sx = 0; sx < 3; ++sx) {
                            int xx = x0 + sx;
                            bool vx = (xx >= 0) & (xx < WX);
                            int xc = min(max(xx, 0), WX - 1);
                            float val = xp[yc * WX + xc];
                            tv[r][sx] = (vy & vx) ? val : 0.f;
                        }
                    }
                }
                float h0[3], h1[3];
                #pragma unroll
                for (int r = 0; r < 3; ++r) {
                    h0[r] = tv[r][0] + fx * (tv[r][1] - tv[r][0]);
                    h1[r] = tv[r][1] + fx * (tv[r][2] - tv[r][1]);
                }
                alds[aoff320(0 * 16 + tq, clocal)] = f2bf(h0[0] + fy * (h0[1] - h0[0]));
                alds[aoff320(1 * 16 + tq, clocal)] = f2bf(h1[0] + fy * (h1[1] - h1[0]));
                alds[aoff320(2 * 16 + tq, clocal)] = f2bf(h0[1] + fy * (h0[2] - h0[1]));
                alds[aoff320(3 * 16 + tq, clocal)] = f2bf(h1[1] + fy * (h1[2] - h1[1]));
            }
        }
        __syncthreads();          // A-tile (288 cols) visible

        // ---- phase 2: D[64px][64oc] += V[64][288] . W^T  (MFMA bf16)
        int arow = w * 16 + lm;
        const unsigned short* bbase = wdtb + (size_t)(h * 64) * 288;
        #pragma unroll
        for (int ks = 0; ks < 9; ++ks) {
            bf16x8 a = *(const bf16x8*)&alds[aoff320(arow, ks * 32 + lq * 8)];
            #pragma unroll
            for (int n = 0; n < 4; ++n) {
                bf16x8 bb = *(const bf16x8*)(bbase + (size_t)(n * 16 + lm) * 288
                                             + ks * 32 + lq * 8);
                acc[n] = __builtin_amdgcn_mfma_f32_16x16x32_bf16(a, bb, acc[n], 0, 0, 0);
            }
        }
    }

    // ---- epilogue via LDS: D lane layout -> [oc][px] -> coalesced stores
    __syncthreads();              // all phase-2 reads of alds complete
    float* dlds = (float*)alds;   // 64*65 = 4160 floats
    #pragma unroll
    for (int n = 0; n < 4; ++n) {
        int oc = n * 16 + lm;
        #pragma unroll
        for (int r = 0; r < 4; ++r) {
            int px = w * 16 + lq * 4 + r;     // = sub*16 + q
            dlds[oc * 65 + px] = acc[n][r];
        }
    }
    __syncthreads();
    {
        int oc = tid >> 2;
        int sy = (tid >> 1) & 1;
        int qh = (tid & 1) * 8;
        float* orow = out + (((size_t)b * 64 + oc) * 128 + 2 * qy + sy) * 128 + 2 * qx0;
        const float* d0 = &dlds[oc * 65 + (sy * 2 + 0) * 16];
        const float* d1 = &dlds[oc * 65 + (sy * 2 + 1) * 16];
        #pragma unroll
        for (int i = 0; i < 8; ++i) {
            int q = qh + i;
            *(float2*)(orow + 2 * q) = make_float2(d0[q], d1[q]);
        }
    }
}

extern "C" void kernel_launch(void* const* d_in, const int* in_sizes, int n_in,
                              void* d_out, int out_size, void* d_ws, size_t ws_size,
                              hipStream_t stream) {
    const float* x  = (const float*)d_in[0];
    const float* w0 = (const float*)d_in[1];
    const float* b0 = (const float*)d_in[2];
    const float* w1 = (const float*)d_in[3];
    const float* b1 = (const float*)d_in[4];
    const float* w2 = (const float*)d_in[5];
    const float* b2 = (const float*)d_in[6];
    const float* w3 = (const float*)d_in[7];
    const float* b3 = (const float*)d_in[8];
    const float* wd = (const float*)d_in[9];
    float* out = (float*)d_out;

    float* ws = (float*)d_ws;
    float* p1    = ws;                       // 1,048,576 floats
    float* t2    = p1 + 1048576;             //   524,288
    float* t3    = t2 + 524288;              //   524,288
    unsigned short* wdtb = (unsigned short*)(t3 + 524288);  // 36,864 + 16 pad
    __half* w3h = (__half*)(wdtb + 36880);   // 36,864 fp16 (16B-aligned)
    unsigned short* w0b = (unsigned short*)(w3h + 36864);   // 40,960 bf16

    k_wdt<<<448, 256, 0, stream>>>(wd, w3, w0, wdtb, w3h, w0b);
    k_conv0_mfma<<<1024, 256, 0, stream>>>(x, w0b, b0, p1);
    k_conv1x1_a<<<1024, 256, 0, stream>>>(p1, w1, b1, t2);
    k_conv3x3_b<<<1024, 256, 0, stream>>>(t2, w2, b2, t3);
    k_deform<<<1024, 256, 0, stream>>>(x, t3, w3h, b3, wdtb, out);
}

// Round 6
// 223.526 us; speedup vs baseline: 1.1797x; 1.0145x over previous
//
#include <hip/hip_runtime.h>
#include <hip/hip_bf16.h>
#include <hip/hip_fp16.h>

// Pipeline:
//  x (4,64,130,130) --conv3x3 valid + bias + maxpool2x2 (MFMA)--> p1 (4,64,64,64)
//  p1 --1x1 conv (64->32, float4-vectorized)--> t2 (4,32,64,64)
//  t2 --3x3 conv pad=1 (32->32, MFMA)--> t3 (4,32,64,64)
//  [FUSED] offset conv (32->1152) computed INSIDE k_deform via f16 MFMA
//  deform_conv(x, upsample2x(offsets), wd) -> out (4,64,128,128)
//
//  Round-6 changes:
//   - k_conv3x3_b -> k_conv3_mfma on the proven conv0_mfma template:
//     8x8 region/block, zero-padded 10x10 staging, K=288 over 2 ci-groups
//     of 144 (+16 zero pad), N=32 (acc[2]), bias in epilogue. Grid 256.
//   - k_conv1x1_a vectorized: 4 px/thread via float4 loads/stores. Grid 256.
//   - k_wdt also packs w2 -> bf16 w2b[cig(2)][oc(32)][160]. Grid 488.
//   - k_deform v5 and k_conv0_mfma untouched (proven).

#define HX 130
#define WX 130

typedef short bf16x8 __attribute__((ext_vector_type(8)));
typedef _Float16 f16x8 __attribute__((ext_vector_type(8)));
typedef float f32x4 __attribute__((ext_vector_type(4)));

static __device__ __forceinline__ unsigned short f2bf(float f) {
    unsigned u = __float_as_uint(f);
    unsigned r = u + 0x7fff + ((u >> 16) & 1);   // round-to-nearest-even
    return (unsigned short)(r >> 16);
}

// A-tile address (in shorts): row pitch 320, 16B-block swizzle (k_deform v5)
static __device__ __forceinline__ int aoff320(int row, int col) {
    return row * 320 + ((((col >> 3) ^ (row & 7))) << 3) + (col & 7);
}

// A-tile address (in shorts): row pitch 192 (conv MFMA, 160 cols)
static __device__ __forceinline__ int aoff192(int row, int col) {
    return row * 192 + ((((col >> 3) ^ (row & 7))) << 3) + (col & 7);
}

// ---------------- K0: weight prep
//  idx <  36864 : wd -> bf16 wdtb[h(2)][oc(64)][col(288)]  (+16 zero tail)
//  idx <  73728 : w3 -> fp16 w3h[1152][32]
//  idx < 114688 : w0 -> bf16 w0b[cig(4)][oc(64)][160]; col=ci_l*9+kk, pad 0
//  idx < 124928 : w2 -> bf16 w2b[cig(2)][oc(32)][160]; col=ci_l*9+kk, pad 0
__global__ __launch_bounds__(256) void k_wdt(const float* __restrict__ wd,
                                             const float* __restrict__ w3,
                                             const float* __restrict__ w0,
                                             const float* __restrict__ w2,
                                             unsigned short* __restrict__ wdtb,
                                             __half* __restrict__ w3h,
                                             unsigned short* __restrict__ w0b,
                                             unsigned short* __restrict__ w2b) {
    int idx = blockIdx.x * 256 + threadIdx.x;   // grid 488*256 = 124928
    if (idx < 36864) {
        int o = idx / 576;
        int rem = idx - o * 576;
        int c = rem / 9;
        int kk = rem - c * 9;
        int h = c >> 5;
        int c5 = c & 31;
        int col = (c5 >> 4) * 144 + ((c5 >> 3) & 1) * 72 + (c5 & 7) * 9 + kk;
        wdtb[(size_t)(h * 64 + o) * 288 + col] = f2bf(wd[idx]);
        if (idx < 16) wdtb[36864 + idx] = 0;    // tail pad
    } else if (idx < 73728) {
        int i2 = idx - 36864;
        w3h[i2] = __float2half_rn(w3[i2]);
    } else if (idx < 114688) {
        int i3 = idx - 73728;                   // 0..40959
        int row = i3 / 160;                     // cig*64 + oc
        int col = i3 - row * 160;
        int cig = row >> 6, oc = row & 63;
        unsigned short v = 0;
        if (col < 144) {
            int ci = (col * 57) >> 9;           // /9, valid col<144
            int kk = col - ci * 9;
            v = f2bf(w0[(size_t)(oc * 64 + cig * 16 + ci) * 9 + kk]);
        }
        w0b[i3] = v;
    } else {
        int i4 = idx - 114688;                  // 0..10239
        int row = i4 / 160;                     // cig*32 + oc
        int col = i4 - row * 160;
        int cig = row >> 5, oc = row & 31;
        unsigned short v = 0;
        if (col < 144) {
            int ci = (col * 57) >> 9;
            int kk = col - ci * 9;
            v = f2bf(w2[(size_t)(oc * 32 + cig * 16 + ci) * 9 + kk]);
        }
        w2b[i4] = v;
    }
}

// ---------------- K1: conv3x3 valid (64->64) via MFMA + bias + maxpool -> p1
// grid 1024 = b(4) * ty(16) * tx(16); block 256 = 4 waves. (round-5 proven)
__global__ __launch_bounds__(256, 4) void k_conv0_mfma(const float* __restrict__ x,
                                                       const unsigned short* __restrict__ w0b,
                                                       const float* __restrict__ b0,
                                                       float* __restrict__ p1) {
    int blk = blockIdx.x;
    int tx = blk & 15;
    int ty = (blk >> 4) & 15;
    int b = blk >> 8;
    int tid = threadIdx.x;
    int w = tid >> 6;
    int lane = tid & 63;
    int lm = lane & 15;
    int lq = lane >> 4;
    int oy0 = ty * 8, ox0 = tx * 8;

    __shared__ __align__(16) unsigned short alds[64 * 192];   // 24576 B
    __shared__ __align__(16) float xlds[1600];                //  6400 B

    f32x4 acc[4];
    #pragma unroll
    for (int n = 0; n < 4; ++n) acc[n] = (f32x4){0.f, 0.f, 0.f, 0.f};

    if (tid < 128) {
        *(bf16x8*)&alds[aoff192(tid >> 1, 144 + (tid & 1) * 8)] =
            (bf16x8){0, 0, 0, 0, 0, 0, 0, 0};
    }

    const float* xb = x + (size_t)(b * 64) * (HX * WX) + oy0 * WX + ox0;
    int apx = tid >> 2;           // 0..63 conv px (py*8+pxx)
    int acq = tid & 3;            // col slice
    int py = apx >> 3, pxx = apx & 7;

    for (int cig = 0; cig < 4; ++cig) {
        #pragma unroll
        for (int j = 0; j < 7; ++j) {
            int i = tid + j * 256;
            if (i < 1600) {
                int ci = i / 100;
                int rem = i - ci * 100;
                int rr = rem / 10, cc = rem - rr * 10;
                xlds[i] = xb[(size_t)(cig * 16 + ci) * (HX * WX) + rr * WX + cc];
            }
        }
        __syncthreads();
        #pragma unroll
        for (int jj = 0; jj < 36; ++jj) {
            int col = acq * 36 + jj;
            int ci = (col * 57) >> 9;     // /9
            int kk = col - ci * 9;
            int ky = kk / 3, kx = kk - ky * 3;
            alds[aoff192(apx, col)] =
                f2bf(xlds[ci * 100 + (py + ky) * 10 + (pxx + kx)]);
        }
        __syncthreads();
        int arow = w * 16 + lm;
        const unsigned short* bbase = w0b + (size_t)cig * 64 * 160;
        #pragma unroll
        for (int ks = 0; ks < 5; ++ks) {
            bf16x8 a = *(const bf16x8*)&alds[aoff192(arow, ks * 32 + lq * 8)];
            #pragma unroll
            for (int n = 0; n < 4; ++n) {
                bf16x8 bb = *(const bf16x8*)(bbase + (size_t)(n * 16 + lm) * 160
                                             + ks * 32 + lq * 8);
                acc[n] = __builtin_amdgcn_mfma_f32_16x16x32_bf16(a, bb, acc[n], 0, 0, 0);
            }
        }
    }

    __syncthreads();
    float* dlds = (float*)alds;   // 64*65 floats
    #pragma unroll
    for (int n = 0; n < 4; ++n) {
        int oc = n * 16 + lm;
        #pragma unroll
        for (int r = 0; r < 4; ++r) {
            int px = w * 16 + lq * 4 + r;
            dlds[oc * 65 + px] = acc[n][r];
        }
    }
    __syncthreads();
    {
        int oc = tid >> 2;
        int ppy = tid & 3;
        float bo = b0[oc];
        float4 o4;
        #pragma unroll
        for (int ppx = 0; ppx < 4; ++ppx) {
            const float* dp = &dlds[oc * 65 + (2 * ppy) * 8 + 2 * ppx];
            float m = fmaxf(fmaxf(dp[0], dp[1]), fmaxf(dp[8], dp[9])) + bo;
            ((float*)&o4)[ppx] = m;
        }
        *(float4*)(p1 + (((size_t)b * 64 + oc) * 64 + ty * 4 + ppy) * 64 + tx * 4) = o4;
    }
}

// ---------------- K2: 1x1 conv 64->32; float4-vectorized, 4 px x 2 oc/thread
// grid 256 = b(4) * cog(16) * qt(4); block 256.
__global__ __launch_bounds__(256) void k_conv1x1_a(const float* __restrict__ p1,
                                                   const float* __restrict__ w1,
                                                   const float* __restrict__ b1,
                                                   float* __restrict__ t2) {
    int blk = blockIdx.x;
    int qt = blk & 3;
    int cog = (blk >> 2) & 15;
    int b = blk >> 6;
    int q = qt * 256 + threadIdx.x;       // quad index 0..1023
    float4 acc[2];
    #pragma unroll
    for (int i = 0; i < 2; ++i) {
        float bv = b1[cog * 2 + i];
        acc[i] = make_float4(bv, bv, bv, bv);
    }
    const float* ip = p1 + (size_t)b * 64 * 4096 + q * 4;
    for (int ci = 0; ci < 64; ++ci) {
        float4 v = *(const float4*)(ip + (size_t)ci * 4096);
        #pragma unroll
        for (int i = 0; i < 2; ++i) {
            float wv = w1[(cog * 2 + i) * 64 + ci];
            acc[i].x += wv * v.x; acc[i].y += wv * v.y;
            acc[i].z += wv * v.z; acc[i].w += wv * v.w;
        }
    }
    float* op = t2 + (size_t)b * 32 * 4096 + q * 4;
    #pragma unroll
    for (int i = 0; i < 2; ++i)
        *(float4*)(op + (size_t)(cog * 2 + i) * 4096) = acc[i];
}

// ---------------- K3: 3x3 conv pad=1 (32->32) via MFMA -> t3
// grid 256 = b(4) * ty(8) * tx(8); block 256 = 4 waves. conv0 template:
// 8x8 region, zero-padded 10x10 staging, K=288 (2 cig x 144+16pad), N=32.
__global__ __launch_bounds__(256, 4) void k_conv3_mfma(const float* __restrict__ t2,
                                                       const unsigned short* __restrict__ w2b,
                                                       const float* __restrict__ b2,
                                                       float* __restrict__ t3) {
    int blk = blockIdx.x;
    int tx = blk & 7;
    int ty = (blk >> 3) & 7;
    int b = blk >> 6;
    int tid = threadIdx.x;
    int w = tid >> 6;
    int lane = tid & 63;
    int lm = lane & 15;
    int lq = lane >> 4;
    int oy0 = ty * 8, ox0 = tx * 8;

    __shared__ __align__(16) unsigned short alds[64 * 192];   // 24576 B
    __shared__ __align__(16) float xlds[1600];                //  6400 B

    f32x4 acc[2];
    #pragma unroll
    for (int n = 0; n < 2; ++n) acc[n] = (f32x4){0.f, 0.f, 0.f, 0.f};

    if (tid < 128) {
        *(bf16x8*)&alds[aoff192(tid >> 1, 144 + (tid & 1) * 8)] =
            (bf16x8){0, 0, 0, 0, 0, 0, 0, 0};
    }

    const float* tb = t2 + (size_t)(b * 32) * 4096;
    int apx = tid >> 2;           // 0..63 out px (py*8+pxx)
    int acq = tid & 3;
    int py = apx >> 3, pxx = apx & 7;

    for (int cig = 0; cig < 2; ++cig) {
        // ---- stage t2 tile: 16 ci x 10 x 10, zero-padded at borders
        #pragma unroll
        for (int j = 0; j < 7; ++j) {
            int i = tid + j * 256;
            if (i < 1600) {
                int ci = i / 100;
                int rem = i - ci * 100;
                int rr = rem / 10, cc = rem - rr * 10;
                int gy = oy0 + rr - 1, gx = ox0 + cc - 1;
                bool ok = (gy >= 0) & (gy < 64) & (gx >= 0) & (gx < 64);
                xlds[i] = ok ? tb[(size_t)(cig * 16 + ci) * 4096 + gy * 64 + gx]
                             : 0.f;
            }
        }
        __syncthreads();          // xlds ready; prev MFMA's alds reads done
        #pragma unroll
        for (int jj = 0; jj < 36; ++jj) {
            int col = acq * 36 + jj;
            int ci = (col * 57) >> 9;     // /9
            int kk = col - ci * 9;
            int ky = kk / 3, kx = kk - ky * 3;
            alds[aoff192(apx, col)] =
                f2bf(xlds[ci * 100 + (py + ky) * 10 + (pxx + kx)]);
        }
        __syncthreads();          // A-tile visible
        int arow = w * 16 + lm;
        const unsigned short* bbase = w2b + (size_t)cig * 32 * 160;
        #pragma unroll
        for (int ks = 0; ks < 5; ++ks) {
            bf16x8 a = *(const bf16x8*)&alds[aoff192(arow, ks * 32 + lq * 8)];
            #pragma unroll
            for (int n = 0; n < 2; ++n) {
                bf16x8 bb = *(const bf16x8*)(bbase + (size_t)(n * 16 + lm) * 160
                                             + ks * 32 + lq * 8);
                acc[n] = __builtin_amdgcn_mfma_f32_16x16x32_bf16(a, bb, acc[n], 0, 0, 0);
            }
        }
    }

    // ---- epilogue: D[64px][32oc] -> LDS [oc][px] -> bias -> t3
    __syncthreads();
    float* dlds = (float*)alds;   // 32*65 floats = 8320 B
    #pragma unroll
    for (int n = 0; n < 2; ++n) {
        int oc = n * 16 + lm;
        #pragma unroll
        for (int r = 0; r < 4; ++r) {
            int px = w * 16 + lq * 4 + r;
            dlds[oc * 65 + px] = acc[n][r];
        }
    }
    __syncthreads();
    {
        int oc = tid >> 3;        // 0..31
        int r = tid & 7;          // out row within region
        float bo = b2[oc];
        const float* dp = &dlds[oc * 65 + r * 8];
        float* op = t3 + ((size_t)(b * 32 + oc) * 64 + oy0 + r) * 64 + ox0;
        float4 a4 = make_float4(dp[0] + bo, dp[1] + bo, dp[2] + bo, dp[3] + bo);
        float4 b4 = make_float4(dp[4] + bo, dp[5] + bo, dp[6] + bo, dp[7] + bo);
        *(float4*)(op) = a4;
        *(float4*)(op + 4) = b4;
    }
}

// ---------------- K5: deformable conv, MFMA offsets + MFMA main (v5, proven)
__global__ __launch_bounds__(256, 3) void k_deform(const float* __restrict__ x,
                                                   const float* __restrict__ t3,
                                                   const __half* __restrict__ w3h,
                                                   const float* __restrict__ b3,
                                                   const unsigned short* __restrict__ wdtb,
                                                   float* __restrict__ out) {
    int blk = blockIdx.x;
    int b = blk & 3;
    int strip = blk >> 2;         // 0..255
    int tid = threadIdx.x;
    int po0 = strip * 16;
    int qy = po0 >> 6;            // strip lies in one quad-row
    int qx0 = po0 & 63;
    int w = tid >> 6;             // wave id
    int lane = tid & 63;
    int lm = lane & 15;
    int lq = lane >> 4;
    int tq = tid & 15;            // pooled-px column this thread serves (fixed)
    int kb = tid >> 4;            // kcol = it*16 + kb

    __shared__ __align__(16) unsigned short alds[64 * 320];   // 40960 B
    __shared__ __align__(16) __half2 soff[2304];              //  9216 B
    __shared__ __align__(16) _Float16 st3t[16 * 40];          //  1280 B

    f32x4 acc[4];
    #pragma unroll
    for (int n = 0; n < 4; ++n) acc[n] = (f32x4){0.f, 0.f, 0.f, 0.f};

    const float* xb = x + (size_t)b * 64 * HX * WX;
    float fybase = (float)(2 * qy);
    float fxbase = (float)(2 * (qx0 + tq));

    // ---- stage t3 tile (32 ci x 16 px) to LDS as fp16, px-major pitch 40
    {
        int px = tid & 15, ci0 = tid >> 4;    // ci0 0..15
        const float* t3p = t3 + (size_t)b * 32 * 4096 + (qy * 64 + qx0 + px);
        st3t[px * 40 + ci0]      = (_Float16)t3p[(size_t)ci0 * 4096];
        st3t[px * 40 + ci0 + 16] = (_Float16)t3p[(size_t)(ci0 + 16) * 4096];
    }
    __syncthreads();
    // B-frag (t3) for the offset MFMA: lane holds t3[px=lm][ci=lq*8+j].
    const f16x8 bfrag = *(const f16x8*)&st3t[lm * 40 + lq * 8];

    for (int h = 0; h < 2; ++h) {
        #pragma unroll 1
        for (int sl = 0; sl < 2; ++sl) {
            int s = h * 2 + sl;           // sup = 16 channels
            __syncthreads();              // alds+soff free (prev phase done)

            // ---- phase 1a: offsets via f16 MFMA. 18 tiles of 16 off-ch.
            #pragma unroll
            for (int rep = 0; rep < 5; ++rep) {
                int t = rep * 4 + w;
                if (rep == 4) { if (w >= 2) break; t = 16 + w; }
                const f16x8 afrag = *(const f16x8*)((const _Float16*)w3h
                        + (size_t)(s * 288 + t * 16 + lm) * 32 + lq * 8);
                f32x4 d = __builtin_amdgcn_mfma_f32_16x16x32_f16(
                        afrag, bfrag, (f32x4){0.f, 0.f, 0.f, 0.f}, 0, 0, 0);
                float4 bq = *(const float4*)(b3 + s * 288 + t * 16 + lq * 4);
                int p0 = (t * 8 + lq * 2) * 16 + lm;   // pair-slot kcol*16+px
                soff[p0]      = __floats2half2_rn(d[0] + bq.x, d[1] + bq.y);
                soff[p0 + 16] = __floats2half2_rn(d[2] + bq.z, d[3] + bq.w);
            }
            __syncthreads();              // soff visible

            // ---- phase 1b: prefetch 9 offset pairs (word = it*256 + tid)
            __half2 o2h[9];
            #pragma unroll
            for (int it = 0; it < 9; ++it)
                o2h[it] = soff[it * 256 + tid];
            // bilinear gather -> 4 bf16 A-tile rows per task
            #pragma unroll
            for (int it = 0; it < 9; ++it) {
                int kcol = it * 16 + kb;      // 0..143
                int lc = kcol >= 72;
                int ckk = kcol - 72 * lc;     // 0..71
                int ch = (ckk * 57) >> 9;     // /9
                int kk = ckk - ch * 9;
                int c = s * 16 + lc * 8 + ch;
                int clocal = sl * 144 + kcol; // A column 0..287
                float2 off = __half22float2(o2h[it]);
                float py = off.x + fybase + (float)(kk / 3);
                float px = off.y + fxbase + (float)(kk % 3);
                float y0f = floorf(py), x0f = floorf(px);
                float fy = py - y0f, fx = px - x0f;
                int y0 = (int)y0f, x0 = (int)x0f;
                const float* xp = xb + (size_t)c * (HX * WX);
                float tv[3][3];
                bool fastok = (y0 >= 0) & (y0 <= HX - 3) & (x0 >= 0) & (x0 <= WX - 3);
                if (__all(fastok)) {
                    // whole wave in-bounds: even-aligned float2 pair per row
                    int xe = x0 & ~1;         // even -> 8B-aligned (WX even)
                    int odd = x0 & 1;
                    const float* rp = xp + y0 * WX + xe;
                    #pragma unroll
                    for (int r = 0; r < 3; ++r) {
                        float2 A = *(const float2*)(rp);
                        float2 B = *(const float2*)(rp + 2);
                        tv[r][0] = odd ? A.y : A.x;
                        tv[r][1] = odd ? B.x : A.y;
                        tv[r][2] = odd ? B.y : B.x;
                        rp += WX;
                    }
                } else {
                    #pragma unroll
                    for (int r = 0; r < 3; ++r) {
                        int yy = y0 + r;
                        bool vy = (yy >= 0) & (yy < HX);
                        int yc = min(max(yy, 0), HX - 1);
                        #pragma unroll
                        for (int sx = 0; sx < 3; ++sx) {
                            int xx = x0 + sx;
                            bool vx = (xx >= 0) & (xx < WX);
                            int xc = min(max(xx, 0), WX - 1);
                            float val = xp[yc * WX + xc];
                            tv[r][sx] = (vy & vx) ? val : 0.f;
                        }
                    }
                }
                float h0[3], h1[3];
                #pragma unroll
                for (int r = 0; r < 3; ++r) {
                    h0[r] = tv[r][0] + fx * (tv[r][1] - tv[r][0]);
                    h1[r] = tv[r][1] + fx * (tv[r][2] - tv[r][1]);
                }
                alds[aoff320(0 * 16 + tq, clocal)] = f2bf(h0[0] + fy * (h0[1] - h0[0]));
                alds[aoff320(1 * 16 + tq, clocal)] = f2bf(h1[0] + fy * (h1[1] - h1[0]));
                alds[aoff320(2 * 16 + tq, clocal)] = f2bf(h0[1] + fy * (h0[2] - h0[1]));
                alds[aoff320(3 * 16 + tq, clocal)] = f2bf(h1[1] + fy * (h1[2] - h1[1]));
            }
        }
        __syncthreads();          // A-tile (288 cols) visible

        // ---- phase 2: D[64px][64oc] += V[64][288] . W^T  (MFMA bf16)
        int arow = w * 16 + lm;
        const unsigned short* bbase = wdtb + (size_t)(h * 64) * 288;
        #pragma unroll
        for (int ks = 0; ks < 9; ++ks) {
            bf16x8 a = *(const bf16x8*)&alds[aoff320(arow, ks * 32 + lq * 8)];
            #pragma unroll
            for (int n = 0; n < 4; ++n) {
                bf16x8 bb = *(const bf16x8*)(bbase + (size_t)(n * 16 + lm) * 288
                                             + ks * 32 + lq * 8);
                acc[n] = __builtin_amdgcn_mfma_f32_16x16x32_bf16(a, bb, acc[n], 0, 0, 0);
            }
        }
    }

    // ---- epilogue via LDS: D lane layout -> [oc][px] -> coalesced stores
    __syncthreads();              // all phase-2 reads of alds complete
    float* dlds = (float*)alds;   // 64*65 = 4160 floats
    #pragma unroll
    for (int n = 0; n < 4; ++n) {
        int oc = n * 16 + lm;
        #pragma unroll
        for (int r = 0; r < 4; ++r) {
            int px = w * 16 + lq * 4 + r;     // = sub*16 + q
            dlds[oc * 65 + px] = acc[n][r];
        }
    }
    __syncthreads();
    {
        int oc = tid >> 2;
        int sy = (tid >> 1) & 1;
        int qh = (tid & 1) * 8;
        float* orow = out + (((size_t)b * 64 + oc) * 128 + 2 * qy + sy) * 128 + 2 * qx0;
        const float* d0 = &dlds[oc * 65 + (sy * 2 + 0) * 16];
        const float* d1 = &dlds[oc * 65 + (sy * 2 + 1) * 16];
        #pragma unroll
        for (int i = 0; i < 8; ++i) {
            int q = qh + i;
            *(float2*)(orow + 2 * q) = make_float2(d0[q], d1[q]);
        }
    }
}

extern "C" void kernel_launch(void* const* d_in, const int* in_sizes, int n_in,
                              void* d_out, int out_size, void* d_ws, size_t ws_size,
                              hipStream_t stream) {
    const float* x  = (const float*)d_in[0];
    const float* w0 = (const float*)d_in[1];
    const float* b0 = (const float*)d_in[2];
    const float* w1 = (const float*)d_in[3];
    const float* b1 = (const float*)d_in[4];
    const float* w2 = (const float*)d_in[5];
    const float* b2 = (const float*)d_in[6];
    const float* w3 = (const float*)d_in[7];
    const float* b3 = (const float*)d_in[8];
    const float* wd = (const float*)d_in[9];
    float* out = (float*)d_out;

    float* ws = (float*)d_ws;
    float* p1    = ws;                       // 1,048,576 floats
    float* t2    = p1 + 1048576;             //   524,288
    float* t3    = t2 + 524288;              //   524,288
    unsigned short* wdtb = (unsigned short*)(t3 + 524288);  // 36,864 + 16 pad
    __half* w3h = (__half*)(wdtb + 36880);   // 36,864 fp16 (16B-aligned)
    unsigned short* w0b = (unsigned short*)(w3h + 36864);   // 40,960 bf16
    unsigned short* w2b = w0b + 40960;                      // 10,240 bf16

    k_wdt<<<488, 256, 0, stream>>>(wd, w3, w0, w2, wdtb, w3h, w0b, w2b);
    k_conv0_mfma<<<1024, 256, 0, stream>>>(x, w0b, b0, p1);
    k_conv1x1_a<<<256, 256, 0, stream>>>(p1, w1, b1, t2);
    k_conv3_mfma<<<256, 256, 0, stream>>>(t2, w2b, b2, t3);
    k_deform<<<1024, 256, 0, stream>>>(x, t3, w3h, b3, wdtb, out);
}